// Round 6
// baseline (145.475 us; speedup 1.0000x reference)
//
#include <hip/hip_runtime.h>
#include <hip/hip_bf16.h>

#pragma clang fp contract(off)

#define NN   230400   // H*W*A
#define NK   128      // gt boxes
#define HW_  25600    // H*W
#define NA   9
#define NBLK 900      // NN/256
#define BINS 8192
#define BCAP 64

// ---- scalar slots in ws (sc has 128 u32; S_WL isolated on its own cacheline) ----
enum { S_FG_ACTIVE=0, S_FG_TH, S_NFG_FINAL, S_BG_ACTIVE, S_BG_TH, S_NUM_EX, S_SMIN };
#define S_WL 64

__device__ __forceinline__ unsigned encf(float f) {
    unsigned u = __float_as_uint(f);
    return (u & 0x80000000u) ? ~u : (u | 0x80000000u);
}
__device__ __forceinline__ float decf(unsigned e) {
    unsigned u = (e & 0x80000000u) ? (e & 0x7FFFFFFFu) : ~e;
    return __uint_as_float(u);
}
// The ONE IoU expression (identical rounding at every use site; contract off).
__device__ __forceinline__ void iou_parts(float4 a, float ba, float4 g, float ga,
                                          float& I, float& D) {
    float iw = fmaxf(fminf(a.z, g.z) - fmaxf(a.x, g.x) + 1.0f, 0.0f);
    float ih = fmaxf(fminf(a.w, g.w) - fmaxf(a.y, g.y) + 1.0f, 0.0f);
    I = iw * ih;
    D = ba + ga - I;          // (ba+ga)-I, same assoc everywhere
}
__device__ __forceinline__ unsigned vbin(float nz) {
    unsigned b = (unsigned)(nz * 8192.0f);
    return b > 8191u ? 8191u : b;
}

__global__ __launch_bounds__(256) void k_init(unsigned* __restrict__ p, int n) {
    int i = blockIdx.x * blockDim.x + threadIdx.x;
    for (; i < n; i += gridDim.x * blockDim.x) p[i] = 0u;
}

// Fused row+col pass, 128 anchors/block, both loops split 2-way across threads.
// Branchless exact IEEE div every iteration (no wave-divergent trigger).
__global__ __launch_bounds__(256) void k_rowcol(
    const float4* __restrict__ anchors, const float4* __restrict__ gt,
    const float* __restrict__ iminfo, float* __restrict__ maxov,
    unsigned char* __restrict__ argm, unsigned* __restrict__ gtm) {
    __shared__ float4 sg[NK];
    __shared__ float  sga[NK];
    __shared__ float4 sa[128];
    __shared__ float  sba[128];          // real ba, or -1 if outside
    __shared__ float  abest[2][128];
    __shared__ unsigned char aidx[2][128];
    __shared__ float  sm[2][NK];
    int t = threadIdx.x;
    if (t < NK) {
        float4 g = gt[t];
        sg[t] = g;
        sga[t] = (g.z - g.x + 1.0f) * (g.w - g.y + 1.0f);
    }
    int base = blockIdx.x * 128;
    if (t < 128) {
        float4 a = anchors[base + t];
        sa[t] = a;
        float imh = iminfo[0], imw = iminfo[1];
        bool ins = (a.x >= 0.0f) && (a.y >= 0.0f) && (a.z < imw) && (a.w < imh);
        float ba = (a.z - a.x + 1.0f) * (a.w - a.y + 1.0f);
        sba[t] = ins ? ba : -1.0f;
    }
    __syncthreads();
    int lo = t & 127, h = t >> 7;        // h uniform per wave
    // ---- phase A: row best/argmax over k-half [h*64, h*64+64) ----
    {
        float4 a = sa[lo];
        float ba = sba[lo];
        float best = -INFINITY; int idx = h * 64;
        for (int kk = 0; kk < 64; ++kk) {
            int k = h * 64 + kk;
            float I, D; iou_parts(a, ba, sg[k], sga[k], I, D);
            float v = I / D;                       // exact IEEE everywhere
            float ov = (ba < 0.0f) ? -1.0f : v;    // outside row = all -1
            bool c = ov > best;                    // strict > = first max
            best = c ? ov : best;
            idx  = c ? k : idx;
        }
        abest[h][lo] = best;
        aidx[h][lo]  = (unsigned char)idx;
    }
    // ---- phase B: column max over anchor-half [h*64, h*64+64) ----
    {
        float4 g = sg[lo];
        float ga = sga[lo];
        float run = -1.0f;
        int j0 = h * 64;
        for (int jj = 0; jj < 64; ++jj) {
            float4 a = sa[j0 + jj];                // wave-uniform -> LDS broadcast
            float ba = sba[j0 + jj];
            float I, D; iou_parts(a, ba, g, ga, I, D);
            float v = I / D;
            float ov = (ba < 0.0f) ? -1.0f : v;
            run = fmaxf(run, ov);
        }
        sm[h][lo] = run;
    }
    __syncthreads();
    if (t < 128) {
        float b0 = abest[0][t], b1 = abest[1][t];
        bool c = b1 > b0;                          // strict: k-half 0 wins ties
        maxov[base + t] = c ? b1 : b0;
        argm[base + t]  = c ? aidx[1][t] : aidx[0][t];
        unsigned e = encf(fmaxf(sm[0][t], sm[1][t]));
        if (e > gtm[t]) atomicMax(&gtm[t], e);     // racy prefilter; atomic authoritative
    }
}

// Sort columns ascending by gt_max (ties by index) + publish smin. 1 block.
__global__ __launch_bounds__(128) void k_sortgt(
    const float4* __restrict__ gt, const unsigned* __restrict__ gtm,
    float4* __restrict__ sgt, float* __restrict__ sgar, float* __restrict__ sgmv,
    unsigned* __restrict__ sc) {
    __shared__ unsigned se[NK];
    int t = threadIdx.x;
    unsigned e = gtm[t];
    se[t] = e;
    __syncthreads();
    int rank = 0;
    for (int j = 0; j < NK; ++j) {
        unsigned ej = se[j];
        rank += (ej < e) || (ej == e && j < t);
    }
    float4 g = gt[t];
    float val = decf(e);
    sgt[rank]  = g;
    sgar[rank] = (g.z - g.x + 1.0f) * (g.w - g.y + 1.0f);
    sgmv[rank] = val;
    if (rank == 0) sc[S_SMIN] = __float_as_uint(val);
}

// Labels A: loop-free. Value-binned hist+bucket (uniform -> no contention).
// Deferred candidates (smin <= mo < 0.7) -> worklist.
__global__ __launch_bounds__(256) void k_labels_a(
    const float* __restrict__ maxov, const float* __restrict__ noise,
    unsigned* __restrict__ sc, float* __restrict__ labels,
    unsigned* __restrict__ hfv, unsigned* __restrict__ hbv,
    float* __restrict__ bfv, float* __restrict__ bbv,
    unsigned* __restrict__ wl) {
    int t = threadIdx.x;
    int i = blockIdx.x * 256 + t;
    float mo = maxov[i];
    bool ins = mo >= 0.0f;
    float smin = __uint_as_float(sc[S_SMIN]);
    float lab = -1.0f;
    if (ins && mo < 0.3f)  lab = 0.0f;
    if (ins && mo >= 0.7f) lab = 1.0f;
    bool defer = ins && (mo >= smin) && (mo < 0.7f);
    labels[i] = lab;                                // provisional if deferred
    float nz = noise[i];
    if (!defer) {
        if (lab == 1.0f) {
            unsigned b = vbin(nz);
            unsigned s = atomicAdd(&hfv[b], 1u);
            if (s < BCAP) bfv[b * BCAP + s] = nz;
        } else if (lab == 0.0f) {
            unsigned b = vbin(nz);
            unsigned s = atomicAdd(&hbv[b], 1u);
            if (s < BCAP) bbv[b * BCAP + s] = nz;
        }
    }
    unsigned long long m = __ballot(defer);
    if (m) {
        int lane = t & 63;
        int leader = __ffsll((unsigned long long)m) - 1;
        unsigned base = 0;
        if (lane == leader) base = atomicAdd(&sc[S_WL], (unsigned)__popcll(m));
        base = __shfl(base, leader, 64);
        if (defer) {
            unsigned off = (unsigned)__popcll(m & ((1ull << lane) - 1ull));
            wl[base + off] = (unsigned)i;
        }
    }
}

// Labels B: resolve gt-best over compacted candidates only (sorted-prune loop).
__global__ __launch_bounds__(256) void k_labels_b(
    const float4* __restrict__ anchors, const float4* __restrict__ sgtb,
    const float* __restrict__ sgab, const float* __restrict__ sgmb,
    const float* __restrict__ maxov, const float* __restrict__ noise,
    const unsigned* __restrict__ wl, float* __restrict__ labels,
    unsigned* __restrict__ hfv, unsigned* __restrict__ hbv,
    float* __restrict__ bfv, float* __restrict__ bbv,
    unsigned* __restrict__ sc) {
    __shared__ float4 sg[NK];
    __shared__ float  sga[NK];
    __shared__ float  sgm[NK];
    int t = threadIdx.x;
    if (t < NK) { sg[t] = sgtb[t]; sga[t] = sgab[t]; sgm[t] = sgmb[t]; }
    __syncthreads();
    unsigned cnt = sc[S_WL];
    for (unsigned j = blockIdx.x * 256 + t; j < cnt; j += gridDim.x * 256) {
        unsigned i = wl[j];
        float4 a = anchors[i];
        float mo = maxov[i];
        float ba = (a.z - a.x + 1.0f) * (a.w - a.y + 1.0f);
        bool gb = false;
        for (int q = 0; q < NK; ++q) {
            float gm = sgm[q];
            if (gm > mo) break;           // ov <= mo < gt_max[q]: can't match
            float I, D; iou_parts(a, ba, sg[q], sga[q], I, D);
            float v = I / D;              // bit-identical to k_rowcol winner
            gb = gb || (v == gm);
        }
        float lab = gb ? 1.0f : (mo < 0.3f ? 0.0f : -1.0f);
        if (gb) labels[i] = 1.0f;
        float nz = noise[i];
        if (lab == 1.0f) {
            unsigned b = vbin(nz);
            unsigned s = atomicAdd(&hfv[b], 1u);
            if (s < BCAP) bfv[b * BCAP + s] = nz;
        } else if (lab == 0.0f) {
            unsigned b = vbin(nz);
            unsigned s = atomicAdd(&hbv[b], 1u);
            if (s < BCAP) bbv[b * BCAP + s] = nz;
        }
    }
}

// Selection body: linear 8192-bin scan -> bin+rem -> exact rank among <=64 values.
// Uniform control flow (no early return) so fg+bg can share one kernel.
__device__ __forceinline__ void sel_body(
    const unsigned* __restrict__ hist, const float* __restrict__ bucket,
    unsigned* __restrict__ sc, int isBg,
    int* csum, int* suf, int* sscal, float* sv) {
    int t = threadIdx.x;
    const unsigned* hp = hist + t * 32;
    int s = 0;
    for (int b = 0; b < 32; ++b) s += (int)hp[b];
    csum[t] = s;
    if (t == 0) { sscal[0] = 0; sscal[1] = 1; }
    __syncthreads();
    if (t == 0) {
        int run = 0;
        for (int c = 255; c >= 0; --c) { suf[c] = run; run += csum[c]; }
        sscal[2] = run;
    }
    __syncthreads();
    int total = sscal[2];
    int k, active;
    if (isBg) {
        int nfg = (int)sc[S_NFG_FINAL];
        int nb = 256 - nfg;
        active = total > nb;
        k = nb < 1 ? 1 : nb;
    } else {
        active = total > 128;
        k = 128;
    }
    if (!active) {
        if (t == 0) {
            if (isBg) { sc[S_BG_ACTIVE] = 0u; sc[S_NUM_EX] = sc[S_NFG_FINAL] + (unsigned)total; }
            else      { sc[S_FG_ACTIVE] = 0u; sc[S_NFG_FINAL] = (unsigned)total; }
        }
    } else {
        int above = suf[t];
        if (above < k && k <= above + csum[t]) {
            int c = above;
            for (int b = 31; b >= 0; --b) {
                int hh = (int)hp[b];
                c += hh;
                if (c >= k) { sscal[0] = t * 32 + b; sscal[1] = k - (c - hh); break; }
            }
        }
    }
    __syncthreads();
    if (active) {                                  // block-uniform condition
        int bstar = sscal[0], rem = sscal[1];
        int cnt = (int)hist[bstar];
        if (cnt > BCAP) cnt = BCAP;
        if (t < BCAP) sv[t] = (t < cnt) ? bucket[bstar * BCAP + t] : -INFINITY;
        __syncthreads();
        if (t < cnt) {
            float v = sv[t];
            int a = 0, b2 = 0;
            for (int q = 0; q < cnt; ++q) { float u = sv[q]; a += (u > v); b2 += (u == v); }
            if (a < rem && rem <= a + b2) {        // v is the k-th largest (tie-exact)
                unsigned nk = (unsigned)(k - rem + a + b2);   // count(score >= th)
                if (isBg) { sc[S_BG_TH] = __float_as_uint(v); sc[S_BG_ACTIVE] = 1u;
                            sc[S_NUM_EX] = sc[S_NFG_FINAL] + nk; }
                else      { sc[S_FG_TH] = __float_as_uint(v); sc[S_FG_ACTIVE] = 1u;
                            sc[S_NFG_FINAL] = nk; }
            }
        }
    }
    __syncthreads();                               // publish sc before next pass
}

__global__ __launch_bounds__(256) void k_select(
    const unsigned* __restrict__ hfv, const float* __restrict__ bfv,
    const unsigned* __restrict__ hbv, const float* __restrict__ bbv,
    unsigned* __restrict__ sc) {
    __shared__ int csum[256];
    __shared__ int suf[256];
    __shared__ int sscal[3];
    __shared__ float sv[BCAP];
    sel_body(hfv, bfv, sc, 0, csum, suf, sscal, sv);
    sel_body(hbv, bbv, sc, 1, csum, suf, sscal, sv);
}

// Final: apply disables, permuted label write, targets, weights
__global__ __launch_bounds__(256) void k_final(
    const float4* __restrict__ anchors, const float4* __restrict__ gt,
    const float* __restrict__ noise, const float* __restrict__ labels,
    const unsigned char* __restrict__ argm, const float* __restrict__ maxov,
    const unsigned* __restrict__ sc,
    float* __restrict__ out0, float4* __restrict__ out1,
    float4* __restrict__ out2, float4* __restrict__ out3) {
    int i = blockIdx.x * 256 + threadIdx.x;
    unsigned fga = sc[S_FG_ACTIVE], bga = sc[S_BG_ACTIVE];
    float thf = __uint_as_float(sc[S_FG_TH]);
    float thb = __uint_as_float(sc[S_BG_TH]);

    // out0: dest-indexed permuted labels. dest i = a*HW + cell; src = cell*NA + a
    {
        int a0 = i / HW_, cell0 = i % HW_;
        int src = cell0 * NA + a0;
        float lab0 = labels[src];
        float nz0 = noise[src];
        if (fga && lab0 == 1.0f && nz0 < thf) lab0 = -1.0f;
        if (bga && lab0 == 0.0f && nz0 < thb) lab0 = -1.0f;
        out0[i] = lab0;
    }

    float lab = labels[i];
    float nz = noise[i];
    if (fga && lab == 1.0f && nz < thf) lab = -1.0f;
    if (bga && lab == 0.0f && nz < thb) lab = -1.0f;

    float4 an = anchors[i];
    float4 g = gt[argm[i]];
    float ew = an.z - an.x + 1.0f, eh = an.w - an.y + 1.0f;
    float ecx = an.x + 0.5f * ew,  ecy = an.y + 0.5f * eh;
    float gw = g.z - g.x + 1.0f,   gh = g.w - g.y + 1.0f;
    float gcx = g.x + 0.5f * gw,   gcy = g.y + 0.5f * gh;
    float t0 = (gcx - ecx) / ew;
    float t1 = (gcy - ecy) / eh;
    float t2 = logf(gw / ew);
    float t3 = logf(gh / eh);
    if (maxov[i] < 0.0f) { t0 = 0.0f; t1 = 0.0f; t2 = 0.0f; t3 = 0.0f; }  // outside
    out1[i] = make_float4(t0, t1, t2, t3);

    float biw = (lab == 1.0f) ? 1.0f : 0.0f;
    out2[i] = make_float4(biw, biw, biw, biw);

    float inv = 1.0f / (float)sc[S_NUM_EX];
    float bow = (lab >= 0.0f) ? inv : 0.0f;
    out3[i] = make_float4(bow, bow, bow, bow);
}

extern "C" void kernel_launch(void* const* d_in, const int* in_sizes, int n_in,
                              void* d_out, int out_size, void* d_ws, size_t ws_size,
                              hipStream_t stream) {
    const float4* anchors = (const float4*)d_in[0];
    const float4* gt      = (const float4*)d_in[1];
    const float*  iminfo  = (const float*)d_in[2];
    const float*  noise   = (const float*)d_in[3];

    float*  out0 = (float*)d_out;                  // NN
    float4* out1 = (float4*)(out0 + NN);           // NN x 4
    float4* out2 = (float4*)(out0 + NN + 4 * NN);  // NN x 4
    float4* out3 = (float4*)(out0 + NN + 8 * NN);  // NN x 4

    // value buckets live in the (not-yet-written) out1/out2 region of d_out
    float* bfv = out0 + NN;                        // BINS*BCAP floats = 2MB
    float* bbv = bfv + BINS * BCAP;                // 2MB more (still < out1+out2 span)

    char* ws = (char*)d_ws;
    unsigned* sc   = (unsigned*)ws;                         // 128 u32 (S_WL at +256B)
    unsigned* gtm  = (unsigned*)(ws + 512);                 // 128 u32
    float*    sgmv = (float*)(ws + 1024);                   // 128 f32
    float*    sgar = (float*)(ws + 1536);                   // 128 f32
    float4*   sgt  = (float4*)(ws + 2048);                  // 128 f4 -> ends 4096
    unsigned* hfv  = (unsigned*)(ws + 4096);                // 8192 u32
    unsigned* hbv  = hfv + BINS;                            // 8192 u32 -> ends 69632
    float* labels  = (float*)(ws + 69632);                  // NN f32
    float* maxov   = labels + NN;                           // NN f32
    unsigned char* argm = (unsigned char*)(maxov + NN);     // NN u8
    unsigned* wl   = (unsigned*)(ws + 2143232);             // NN u32 worklist

    k_init<<<68, 256, 0, stream>>>((unsigned*)ws, 17408);   // sc+gtm+sorted+hists
    k_rowcol<<<1800, 256, 0, stream>>>(anchors, gt, iminfo, maxov, argm, gtm);
    k_sortgt<<<1, 128, 0, stream>>>(gt, gtm, sgt, sgar, sgmv, sc);
    k_labels_a<<<NBLK, 256, 0, stream>>>(maxov, noise, sc, labels, hfv, hbv, bfv, bbv, wl);
    k_labels_b<<<256, 256, 0, stream>>>(anchors, sgt, sgar, sgmv, maxov, noise, wl,
                                        labels, hfv, hbv, bfv, bbv, sc);
    k_select<<<1, 256, 0, stream>>>(hfv, bfv, hbv, bbv, sc);
    k_final<<<NBLK, 256, 0, stream>>>(anchors, gt, noise, labels, argm, maxov, sc,
                                      out0, out1, out2, out3);
}

// Round 7
// 81.454 us; speedup vs baseline: 1.7860x; 1.7860x over previous
//
#include <hip/hip_runtime.h>
#include <hip/hip_bf16.h>

#pragma clang fp contract(off)

#define NN   230400   // H*W*A
#define NK   128      // gt boxes
#define HW_  25600    // H*W
#define NA   9
#define NBLK 900      // NN/256
#define BINS 8192
#define BCAP 64

// ---- scalar slots in ws ----
enum { S_FG_ACTIVE=0, S_FG_TH, S_NFG_FINAL, S_BG_ACTIVE, S_BG_TH, S_NUM_EX };

__device__ __forceinline__ unsigned encf(float f) {
    unsigned u = __float_as_uint(f);
    return (u & 0x80000000u) ? ~u : (u | 0x80000000u);
}
__device__ __forceinline__ float decf(unsigned e) {
    unsigned u = (e & 0x80000000u) ? (e & 0x7FFFFFFFu) : ~e;
    return __uint_as_float(u);
}
// The ONE IoU expression (identical rounding at every use site; contract off).
__device__ __forceinline__ void iou_parts(float4 a, float ba, float4 g, float ga,
                                          float& I, float& D) {
    float iw = fmaxf(fminf(a.z, g.z) - fmaxf(a.x, g.x) + 1.0f, 0.0f);
    float ih = fmaxf(fminf(a.w, g.w) - fmaxf(a.y, g.y) + 1.0f, 0.0f);
    I = iw * ih;
    D = ba + ga - I;          // (ba+ga)-I, same assoc everywhere
}
__device__ __forceinline__ unsigned vbin(float nz) {
    unsigned b = (unsigned)(nz * 8192.0f);
    return b > 8191u ? 8191u : b;
}

__global__ __launch_bounds__(256) void k_init(unsigned* __restrict__ p, int n) {
    int i = blockIdx.x * blockDim.x + threadIdx.x;
    for (; i < n; i += gridDim.x * blockDim.x) p[i] = 0u;
}

// Fused row+col pass, 128 anchors/block, 2-way split. Rational (I,D) running max
// with guarded cross-mult compare; exact IEEE div only on rare ambiguity + finals.
// Clear-path update iff rounded-strictly-greater => reference first-max semantics.
__global__ __launch_bounds__(256) void k_rowcol(
    const float4* __restrict__ anchors, const float4* __restrict__ gt,
    const float* __restrict__ iminfo, float* __restrict__ maxov,
    unsigned char* __restrict__ argm, unsigned* __restrict__ gtm) {
    __shared__ float4 sg[NK];
    __shared__ float  sga[NK];
    __shared__ float4 sa[128];
    __shared__ float  sba[128];          // real ba, or -1 if outside
    __shared__ float  abI[2][128], abD[2][128];
    __shared__ unsigned char aidx[2][128];
    __shared__ float  smI[2][NK], smD[2][NK];
    int t = threadIdx.x;
    if (t < NK) {
        float4 g = gt[t];
        sg[t] = g;
        sga[t] = (g.z - g.x + 1.0f) * (g.w - g.y + 1.0f);
    }
    int base = blockIdx.x * 128;
    if (t < 128) {
        float4 a = anchors[base + t];
        sa[t] = a;
        float imh = iminfo[0], imw = iminfo[1];
        bool ins = (a.x >= 0.0f) && (a.y >= 0.0f) && (a.z < imw) && (a.w < imh);
        float ba = (a.z - a.x + 1.0f) * (a.w - a.y + 1.0f);
        sba[t] = ins ? ba : -1.0f;
    }
    __syncthreads();
    int lo = t & 127, h = t >> 7;        // h uniform per wave
    // ---- phase A: row rational best/argmax over k-half [h*64, h*64+64) ----
    {
        float4 a = sa[lo];
        float ba = sba[lo];
        bool ins = ba >= 0.0f;
        float Ib = 0.0f, Db = 1.0f;      // value 0 at first index of half
        int idx = h * 64;
        for (int kk = 0; kk < 64; ++kk) {
            int k = h * 64 + kk;
            float I, D; iou_parts(a, ba, sg[k], sga[k], I, D);
            if (ins && I > 0.0f) {                     // zeros never beat best>=0
                float c1 = I * Db, c2 = Ib * D;
                if (c1 > c2 * (1.0f - 1e-6f)) {
                    if (c1 > c2 * (1.0f + 1e-6f)) {    // provably rounded-greater
                        Ib = I; Db = D; idx = k;
                    } else {                           // ambiguous: exact resolve
                        float vn = I / D, vb = Ib / Db;
                        if (vn > vb) { Ib = I; Db = D; idx = k; }
                    }
                }
            }
        }
        abI[h][lo] = Ib; abD[h][lo] = Db;
        aidx[h][lo] = (unsigned char)idx;
    }
    // ---- phase B: column rational max over anchor-half [h*64, h*64+64) ----
    {
        float4 g = sg[lo];
        float ga = sga[lo];
        float Ib = 0.0f, Db = 1.0f;      // block col max >= 0 contribution (safe)
        int j0 = h * 64;
        for (int jj = 0; jj < 64; ++jj) {
            float4 a = sa[j0 + jj];                    // wave-uniform -> broadcast
            float ba = sba[j0 + jj];
            float I, D; iou_parts(a, ba, g, ga, I, D);
            if (ba >= 0.0f && I > 0.0f) {
                float c1 = I * Db, c2 = Ib * D;
                if (c1 > c2 * (1.0f - 1e-6f)) {
                    if (c1 > c2 * (1.0f + 1e-6f)) { Ib = I; Db = D; }
                    else {
                        float vn = I / D, vb = Ib / Db;
                        if (vn > vb) { Ib = I; Db = D; }
                    }
                }
            }
        }
        smI[h][lo] = Ib; smD[h][lo] = Db;
    }
    __syncthreads();
    if (t < 128) {
        float v0 = abI[0][t] / abD[0][t];              // exact rounded half-max
        float v1 = abI[1][t] / abD[1][t];
        bool outs = sba[t] < 0.0f;
        bool c = v1 > v0;                              // strict: half 0 wins ties
        float best = c ? v1 : v0;
        int idx = c ? aidx[1][t] : aidx[0][t];
        maxov[base + t] = outs ? -1.0f : best;
        argm[base + t]  = (unsigned char)(outs ? 0 : idx);
        float w0 = smI[0][t] / smD[0][t];
        float w1 = smI[1][t] / smD[1][t];
        unsigned e = encf(fmaxf(w0, w1));
        if (e > gtm[t]) atomicMax(&gtm[t], e);         // racy prefilter; atomic wins
    }
}

// Sort columns ascending by gt_max (ties by index). 1 block.
__global__ __launch_bounds__(128) void k_sortgt(
    const float4* __restrict__ gt, const unsigned* __restrict__ gtm,
    float4* __restrict__ sgt, float* __restrict__ sgar, float* __restrict__ sgmv) {
    __shared__ unsigned se[NK];
    int t = threadIdx.x;
    unsigned e = gtm[t];
    se[t] = e;
    __syncthreads();
    int rank = 0;
    for (int j = 0; j < NK; ++j) {
        unsigned ej = se[j];
        rank += (ej < e) || (ej == e && j < t);
    }
    float4 g = gt[t];
    sgt[rank]  = g;
    sgar[rank] = (g.z - g.x + 1.0f) * (g.w - g.y + 1.0f);
    sgmv[rank] = decf(e);
}

// Labels (merged): thresholds from maxov; gt-best resolved INLINE for the few
// deferred anchors (mo in [smin, 0.7)); value-binned hist+bucket for subsampling.
__global__ __launch_bounds__(256) void k_labels(
    const float4* __restrict__ anchors, const float4* __restrict__ sgtb,
    const float* __restrict__ sgab, const float* __restrict__ sgmb,
    const float* __restrict__ maxov, const float* __restrict__ noise,
    float* __restrict__ labels,
    unsigned* __restrict__ hfv, unsigned* __restrict__ hbv,
    float* __restrict__ bfv, float* __restrict__ bbv) {
    __shared__ float4 sg[NK];
    __shared__ float  sga[NK];
    __shared__ float  sgm[NK];
    int t = threadIdx.x;
    if (t < NK) { sg[t] = sgtb[t]; sga[t] = sgab[t]; sgm[t] = sgmb[t]; }
    __syncthreads();
    int i = blockIdx.x * 256 + t;
    float mo = maxov[i];
    bool ins = mo >= 0.0f;
    float smin = sgm[0];
    float lab = -1.0f;
    if (ins && mo < 0.3f)  lab = 0.0f;
    if (ins && mo >= 0.7f) lab = 1.0f;
    bool defer = ins && (mo >= smin) && (mo < 0.7f);
    if (defer) {                               // rare -> divergence cost small
        float4 a = anchors[i];
        float ba = (a.z - a.x + 1.0f) * (a.w - a.y + 1.0f);
        bool gb = false;
        for (int q = 0; q < NK; ++q) {
            float gm = sgm[q];
            if (gm > mo) break;                // sorted: no later column can match
            float I, D; iou_parts(a, ba, sg[q], sga[q], I, D);
            float v = I / D;                   // bit-identical to k_rowcol rounding
            gb = gb || (v == gm);
        }
        if (gb) lab = 1.0f;
    }
    labels[i] = lab;
    float nz = noise[i];
    if (lab == 1.0f) {
        unsigned b = vbin(nz);
        unsigned s = atomicAdd(&hfv[b], 1u);
        if (s < BCAP) bfv[b * BCAP + s] = nz;
    } else if (lab == 0.0f) {
        unsigned b = vbin(nz);
        unsigned s = atomicAdd(&hbv[b], 1u);
        if (s < BCAP) bbv[b * BCAP + s] = nz;
    }
}

// Selection body: linear 8192-bin scan -> bin+rem -> exact rank among <=64 values.
__device__ __forceinline__ void sel_body(
    const unsigned* __restrict__ hist, const float* __restrict__ bucket,
    unsigned* __restrict__ sc, int isBg,
    int* csum, int* suf, int* sscal, float* sv) {
    int t = threadIdx.x;
    const unsigned* hp = hist + t * 32;
    int s = 0;
    for (int b = 0; b < 32; ++b) s += (int)hp[b];
    csum[t] = s;
    if (t == 0) { sscal[0] = 0; sscal[1] = 1; }
    __syncthreads();
    if (t == 0) {
        int run = 0;
        for (int c = 255; c >= 0; --c) { suf[c] = run; run += csum[c]; }
        sscal[2] = run;
    }
    __syncthreads();
    int total = sscal[2];
    int k, active;
    if (isBg) {
        int nfg = (int)sc[S_NFG_FINAL];
        int nb = 256 - nfg;
        active = total > nb;
        k = nb < 1 ? 1 : nb;
    } else {
        active = total > 128;
        k = 128;
    }
    if (!active) {
        if (t == 0) {
            if (isBg) { sc[S_BG_ACTIVE] = 0u; sc[S_NUM_EX] = sc[S_NFG_FINAL] + (unsigned)total; }
            else      { sc[S_FG_ACTIVE] = 0u; sc[S_NFG_FINAL] = (unsigned)total; }
        }
    } else {
        int above = suf[t];
        if (above < k && k <= above + csum[t]) {
            int c = above;
            for (int b = 31; b >= 0; --b) {
                int hh = (int)hp[b];
                c += hh;
                if (c >= k) { sscal[0] = t * 32 + b; sscal[1] = k - (c - hh); break; }
            }
        }
    }
    __syncthreads();
    if (active) {                                  // block-uniform condition
        int bstar = sscal[0], rem = sscal[1];
        int cnt = (int)hist[bstar];
        if (cnt > BCAP) cnt = BCAP;
        if (t < BCAP) sv[t] = (t < cnt) ? bucket[bstar * BCAP + t] : -INFINITY;
        __syncthreads();
        if (t < cnt) {
            float v = sv[t];
            int a = 0, b2 = 0;
            for (int q = 0; q < cnt; ++q) { float u = sv[q]; a += (u > v); b2 += (u == v); }
            if (a < rem && rem <= a + b2) {        // v is the k-th largest (tie-exact)
                unsigned nk = (unsigned)(k - rem + a + b2);   // count(score >= th)
                if (isBg) { sc[S_BG_TH] = __float_as_uint(v); sc[S_BG_ACTIVE] = 1u;
                            sc[S_NUM_EX] = sc[S_NFG_FINAL] + nk; }
                else      { sc[S_FG_TH] = __float_as_uint(v); sc[S_FG_ACTIVE] = 1u;
                            sc[S_NFG_FINAL] = nk; }
            }
        }
    }
    __syncthreads();                               // publish sc before next pass
}

__global__ __launch_bounds__(256) void k_select(
    const unsigned* __restrict__ hfv, const float* __restrict__ bfv,
    const unsigned* __restrict__ hbv, const float* __restrict__ bbv,
    unsigned* __restrict__ sc) {
    __shared__ int csum[256];
    __shared__ int suf[256];
    __shared__ int sscal[3];
    __shared__ float sv[BCAP];
    sel_body(hfv, bfv, sc, 0, csum, suf, sscal, sv);
    sel_body(hbv, bbv, sc, 1, csum, suf, sscal, sv);
}

// Final: apply disables, permuted label write, targets, weights
__global__ __launch_bounds__(256) void k_final(
    const float4* __restrict__ anchors, const float4* __restrict__ gt,
    const float* __restrict__ noise, const float* __restrict__ labels,
    const unsigned char* __restrict__ argm, const float* __restrict__ maxov,
    const unsigned* __restrict__ sc,
    float* __restrict__ out0, float4* __restrict__ out1,
    float4* __restrict__ out2, float4* __restrict__ out3) {
    int i = blockIdx.x * 256 + threadIdx.x;
    unsigned fga = sc[S_FG_ACTIVE], bga = sc[S_BG_ACTIVE];
    float thf = __uint_as_float(sc[S_FG_TH]);
    float thb = __uint_as_float(sc[S_BG_TH]);

    // out0: dest-indexed permuted labels. dest i = a*HW + cell; src = cell*NA + a
    {
        int a0 = i / HW_, cell0 = i % HW_;
        int src = cell0 * NA + a0;
        float lab0 = labels[src];
        float nz0 = noise[src];
        if (fga && lab0 == 1.0f && nz0 < thf) lab0 = -1.0f;
        if (bga && lab0 == 0.0f && nz0 < thb) lab0 = -1.0f;
        out0[i] = lab0;
    }

    float lab = labels[i];
    float nz = noise[i];
    if (fga && lab == 1.0f && nz < thf) lab = -1.0f;
    if (bga && lab == 0.0f && nz < thb) lab = -1.0f;

    float4 an = anchors[i];
    float4 g = gt[argm[i]];
    float ew = an.z - an.x + 1.0f, eh = an.w - an.y + 1.0f;
    float ecx = an.x + 0.5f * ew,  ecy = an.y + 0.5f * eh;
    float gw = g.z - g.x + 1.0f,   gh = g.w - g.y + 1.0f;
    float gcx = g.x + 0.5f * gw,   gcy = g.y + 0.5f * gh;
    float t0 = (gcx - ecx) / ew;
    float t1 = (gcy - ecy) / eh;
    float t2 = logf(gw / ew);
    float t3 = logf(gh / eh);
    if (maxov[i] < 0.0f) { t0 = 0.0f; t1 = 0.0f; t2 = 0.0f; t3 = 0.0f; }  // outside
    out1[i] = make_float4(t0, t1, t2, t3);

    float biw = (lab == 1.0f) ? 1.0f : 0.0f;
    out2[i] = make_float4(biw, biw, biw, biw);

    float inv = 1.0f / (float)sc[S_NUM_EX];
    float bow = (lab >= 0.0f) ? inv : 0.0f;
    out3[i] = make_float4(bow, bow, bow, bow);
}

extern "C" void kernel_launch(void* const* d_in, const int* in_sizes, int n_in,
                              void* d_out, int out_size, void* d_ws, size_t ws_size,
                              hipStream_t stream) {
    const float4* anchors = (const float4*)d_in[0];
    const float4* gt      = (const float4*)d_in[1];
    const float*  iminfo  = (const float*)d_in[2];
    const float*  noise   = (const float*)d_in[3];

    float*  out0 = (float*)d_out;                  // NN
    float4* out1 = (float4*)(out0 + NN);           // NN x 4
    float4* out2 = (float4*)(out0 + NN + 4 * NN);  // NN x 4
    float4* out3 = (float4*)(out0 + NN + 8 * NN);  // NN x 4

    // value buckets live in the (not-yet-written) out1/out2 region of d_out:
    // written by k_labels, read by k_select, then k_final overwrites out1/out2.
    float* bfv = out0 + NN;                        // BINS*BCAP floats = 2MB
    float* bbv = bfv + BINS * BCAP;                // 2MB more

    char* ws = (char*)d_ws;
    unsigned* sc   = (unsigned*)ws;                         // 128 u32
    unsigned* gtm  = (unsigned*)(ws + 512);                 // 128 u32
    float*    sgmv = (float*)(ws + 1024);                   // 128 f32
    float*    sgar = (float*)(ws + 1536);                   // 128 f32
    float4*   sgt  = (float4*)(ws + 2048);                  // 128 f4 -> ends 4096
    unsigned* hfv  = (unsigned*)(ws + 4096);                // 8192 u32
    unsigned* hbv  = hfv + BINS;                            // 8192 u32 -> ends 69632
    float* labels  = (float*)(ws + 69632);                  // NN f32
    float* maxov   = labels + NN;                           // NN f32
    unsigned char* argm = (unsigned char*)(maxov + NN);     // NN u8

    k_init<<<68, 256, 0, stream>>>((unsigned*)ws, 17408);   // sc+gtm+sorted+hists
    k_rowcol<<<1800, 256, 0, stream>>>(anchors, gt, iminfo, maxov, argm, gtm);
    k_sortgt<<<1, 128, 0, stream>>>(gt, gtm, sgt, sgar, sgmv);
    k_labels<<<NBLK, 256, 0, stream>>>(anchors, sgt, sgar, sgmv, maxov, noise,
                                       labels, hfv, hbv, bfv, bbv);
    k_select<<<1, 256, 0, stream>>>(hfv, bfv, hbv, bbv, sc);
    k_final<<<NBLK, 256, 0, stream>>>(anchors, gt, noise, labels, argm, maxov, sc,
                                      out0, out1, out2, out3);
}